// Round 30
// baseline (90.543 us; speedup 1.0000x reference)
//
#include <hip/hip_runtime.h>
#include <hip/hip_fp16.h>
#include <stdint.h>

// MaskCrossAttention: B=4, LQ=LKV=1024, C=EMBED=768, NH=12, HD=64, SCALE=0.125
// Round 29: A/B — attn reverted to KVBLK=32 (r26/r27 verbatim: 3 blocks/CU,
// 46us isolated profile) while keeping r28's BK=64 GEMMs. r28's attn-64
// profiled SLOWER (58 vs 46) yet total improved — isolated profile vs graph
// disagree; this isolates the attn tile choice at the best-known rest-config.

typedef _Float16 f16;
typedef __attribute__((ext_vector_type(8))) _Float16 f16x8;
typedef __attribute__((ext_vector_type(4))) _Float16 f16x4;
typedef __attribute__((ext_vector_type(4))) float f32x4;

__device__ __forceinline__ void gload16(const void* g, void* l) {
  __builtin_amdgcn_global_load_lds(
      (__attribute__((address_space(1))) void*)(uintptr_t)g,
      (__attribute__((address_space(3))) void*)(uint32_t)(uintptr_t)l,
      16, 0, 0);
}

// ---------------- fused prep: cvt Xq, cvt Xkv, transpose Wq/Wkv/Wp ----------
__device__ __forceinline__ void cvt4_job(const float* __restrict__ in,
                                         f16* __restrict__ out, int i) {
  float4 v = reinterpret_cast<const float4*>(in)[i];
  f16x4 o = {(f16)v.x, (f16)v.y, (f16)v.z, (f16)v.w};
  reinterpret_cast<f16x4*>(out)[i] = o;
}
__device__ __forceinline__ void transw_job(const float* __restrict__ W,
                                           f16* __restrict__ Wt, int N, int bid,
                                           int tid) {
  int kcb = bid % 96;  // 96 = 768/8
  int n = (bid / 96) * 256 + tid;
  int k0 = kcb * 8;
  f16x8 o;
#pragma unroll
  for (int j = 0; j < 8; ++j) o[j] = (f16)W[(size_t)(k0 + j) * N + n];
  *reinterpret_cast<f16x8*>(Wt + (size_t)n * 768 + k0) = o;
}
__global__ __launch_bounds__(256) void prep_kernel(
    const float* __restrict__ Xq, const float* __restrict__ Xkv,
    const float* __restrict__ Wq, const float* __restrict__ Wkv,
    const float* __restrict__ Wp, f16* __restrict__ Xq_h,
    f16* __restrict__ Xkv_h, f16* __restrict__ WqT, f16* __restrict__ WkvT,
    f16* __restrict__ WpT) {
  const int bid = blockIdx.x, tid = threadIdx.x;
  if (bid < 3072) cvt4_job(Xq, Xq_h, bid * 256 + tid);
  else if (bid < 6144) cvt4_job(Xkv, Xkv_h, (bid - 3072) * 256 + tid);
  else if (bid < 6432) transw_job(Wq, WqT, 768, bid - 6144, tid);
  else if (bid < 7008) transw_job(Wkv, WkvT, 1536, bid - 6432, tid);
  else transw_job(Wp, WpT, 768, bid - 7008, tid);
}

// --- GEMM body: C = A(4096x768)*Bt(N x 768)^T + bias, tile BMxBNxBK --------
// 4 waves (2x2); double-buffered LDS; coalesced staging:
//   LDS [row][CPR=BK/8][8 f16]; stage content chunk (c)^(row&(CPR-1));
//   read chunk (ks*4+grp)^(row&(CPR-1)).
// Schedule (safe): stage(next) BEFORE compute(cur); ONE __syncthreads/K-step.
template <int BM, int BN, int BK, int NDIM, int EPI>
__device__ __forceinline__ void gemm_body(int bid, f16* As0, f16* Bs0,
                                          f16* As1, f16* Bs1,
                                          const f16* __restrict__ A,
                                          const f16* __restrict__ Bt,
                                          const float* __restrict__ bias,
                                          void* __restrict__ out0,
                                          void* __restrict__ out1) {
  constexpr int KD = 768;
  constexpr int NK = KD / BK;                // K-steps (even)
  constexpr int CPR = BK / 8;                // 16B chunks per row
  constexpr int FM = BM / 32, FN = BN / 32;  // fragments per wave
  const int t = threadIdx.x;
  const int lane = t & 63, wid = t >> 6;
  const int bm = bid / (NDIM / BN), bn = bid % (NDIM / BN);
  const int m0 = bm * BM, n0 = bn * BN;
  const int wm = wid >> 1, wn = wid & 1;
  const int cr = lane & 15, grp = lane >> 4;
  f32x4 acc[FM][FN] = {};

  auto stageAB = [&](f16* As, f16* Bs, int k0) {
#pragma unroll
    for (int i = 0; i < BM * CPR / 256; ++i) {
      int ca = i * 256 + t;
      int row = ca / CPR, kcs = (ca % CPR) ^ (row & (CPR - 1));
      gload16(A + (size_t)(m0 + row) * KD + k0 + kcs * 8, As + ca * 8);
    }
#pragma unroll
    for (int i = 0; i < BN * CPR / 256; ++i) {
      int cb = i * 256 + t;
      int row = cb / CPR, kcs = (cb % CPR) ^ (row & (CPR - 1));
      gload16(Bt + (size_t)(n0 + row) * KD + k0 + kcs * 8, Bs + cb * 8);
    }
  };
  auto computeK = [&](const f16* As, const f16* Bs) {
#pragma unroll
    for (int ks = 0; ks < BK / 32; ++ks) {
      f16x8 af[FM], bf[FN];
#pragma unroll
      for (int mf = 0; mf < FM; ++mf) {
        int r = wm * (BM / 2) + mf * 16 + cr;
        af[mf] = *reinterpret_cast<const f16x8*>(
            As + (r * CPR + ((ks * 4 + grp) ^ (r & (CPR - 1)))) * 8);
      }
#pragma unroll
      for (int nf = 0; nf < FN; ++nf) {
        int rn = wn * (BN / 2) + nf * 16 + cr;
        bf[nf] = *reinterpret_cast<const f16x8*>(
            Bs + (rn * CPR + ((ks * 4 + grp) ^ (rn & (CPR - 1)))) * 8);
      }
#pragma unroll
      for (int mf = 0; mf < FM; ++mf)
#pragma unroll
        for (int nf = 0; nf < FN; ++nf)
          acc[mf][nf] = __builtin_amdgcn_mfma_f32_16x16x32_f16(
              af[mf], bf[nf], acc[mf][nf], 0, 0, 0);
    }
  };

  stageAB(As0, Bs0, 0);
  __syncthreads();
  for (int te = 0; te < NK; te += 2) {
    stageAB(As1, Bs1, (te + 1) * BK);  // in flight during compute(As0)
    computeK(As0, Bs0);
    __syncthreads();                   // drain + barrier + fences
    if (te + 2 < NK) stageAB(As0, Bs0, (te + 2) * BK);
    computeK(As1, Bs1);
    __syncthreads();
  }

#pragma unroll
  for (int mf = 0; mf < FM; ++mf) {
    int m = m0 + wm * (BM / 2) + mf * 16 + grp * 4;  // +r per reg
    int b = m >> 10, lrow = m & 1023;
#pragma unroll
    for (int nf = 0; nf < FN; ++nf) {
      int n = n0 + wn * (BN / 2) + nf * 16 + cr;
      float bv = bias[n];
      f32x4 v = acc[mf][nf];
      if constexpr (EPI == 0) {
        int h = n >> 6, d = n & 63;
        f16* dst = (f16*)out0 + (((size_t)b * 12 + h) * 1024 + lrow) * 64 + d;
#pragma unroll
        for (int r = 0; r < 4; ++r) dst[(size_t)r * 64] = (f16)((v[r] + bv) * 0.125f);
      } else if constexpr (EPI == 1) {
        if (n < 768) {
          int h = n >> 6, d = n & 63;
          f16* dst = (f16*)out0 + (((size_t)b * 12 + h) * 1024 + lrow) * 64 + d;
#pragma unroll
          for (int r = 0; r < 4; ++r) dst[(size_t)r * 64] = (f16)(v[r] + bv);
        } else {
          int n2 = n - 768;
          int h = n2 >> 6, d = n2 & 63;
          f16x4 o;
#pragma unroll
          for (int r = 0; r < 4; ++r) o[r] = (f16)(v[r] + bv);
          *reinterpret_cast<f16x4*>((f16*)out1 + (((size_t)b * 12 + h) * 64 + d) * 1024 + lrow) = o;
        }
      } else {
        float* dst = (float*)out0 + (size_t)m * 768 + n;
#pragma unroll
        for (int r = 0; r < 4; ++r) dst[(size_t)r * 768] = v[r] + bv;
      }
    }
  }
}

// merged Q + KV projection: 128x128x64, dbuf -> 576 blocks, 64KB LDS (r27)
__global__ __launch_bounds__(256) void gemm_qkv_kernel(
    const f16* __restrict__ Xq_h, const f16* __restrict__ WqT,
    const float* __restrict__ bq, f16* __restrict__ Qb,
    const f16* __restrict__ Xkv_h, const f16* __restrict__ WkvT,
    const float* __restrict__ bkv, f16* __restrict__ Kb, f16* __restrict__ VTb) {
  __shared__ f16 As0[8192], Bs0[8192], As1[8192], Bs1[8192];
  const int swz = (blockIdx.x % 8) * 72 + blockIdx.x / 8;  // 576 = 8*72
  if (swz < 192)
    gemm_body<128, 128, 64, 768, 0>(swz, As0, Bs0, As1, Bs1, Xq_h, WqT, bq, Qb,
                                    nullptr);
  else
    gemm_body<128, 128, 64, 1536, 1>(swz - 192, As0, Bs0, As1, Bs1, Xkv_h,
                                     WkvT, bkv, Kb, VTb);
}

// output projection: 64x64x64, dbuf -> 768 blocks, 32KB LDS (r28)
__global__ __launch_bounds__(256) void gemm_out_kernel(
    const f16* __restrict__ attO, const f16* __restrict__ WpT,
    const float* __restrict__ bp, float* __restrict__ out) {
  __shared__ f16 As0[4096], Bs0[4096], As1[4096], Bs1[4096];
  const int swz = (blockIdx.x % 8) * 96 + blockIdx.x / 8;  // 768 = 8*96
  gemm_body<64, 64, 64, 768, 2>(swz, As0, Bs0, As1, Bs1, attO, WpT, bp, out,
                                nullptr);
}

// -------- fused flash attention (r26/r27 verbatim: KVBLK=32, safe sync) ----
__global__ __launch_bounds__(256, 3) void attn_kernel(
    const f16* __restrict__ Q, const f16* __restrict__ K,
    const f16* __restrict__ VT, const float* __restrict__ pos,
    const float* __restrict__ mask, f16* __restrict__ attO) {
  __shared__ f16 KsA[2048], KsB[2048];   // [kv32][c8][8 f16]
  __shared__ f16 VsA[2048], VsB[2048];   // [d64][p4][8 f16]
  __shared__ float PsA[2048], PsB[2048]; // [q64][c8][4 f32]
  const int t = threadIdx.x;
  const int lane = t & 63, wid = t >> 6;
  const int xcd = blockIdx.x & 7;
  const int j = blockIdx.x >> 3;            // 0..95
  const int gidx = xcd * 24 + (j >> 2);     // 0..191 = h*16 + qtile
  const int b = j & 3;
  const int h = gidx >> 4;
  const int qt = gidx & 15;
  const int bh = b * 12 + h;
  const int cq = lane & 15, grp = lane >> 4;
  const int q = qt * 64 + wid * 16 + cq;
  const f16* Qp = Q + ((size_t)bh * 1024 + q) * 64 + grp * 8;
  const f16x8 qf0 = *reinterpret_cast<const f16x8*>(Qp);
  const f16x8 qf1 = *reinterpret_cast<const f16x8*>(Qp + 32);
  const f16* Kb = K + (size_t)bh * 65536;
  const f16* Vb = VT + (size_t)bh * 65536;
  const float* pblk = pos + ((size_t)h * 1024 + qt * 64) * 1024;

  float m_run = -1e30f, l_part = 0.f;  // l_part: per-lane partial sum
  f32x4 acc[4] = {};  // O^T: acc[df][r] -> d = df*16 + grp*4 + r, col q

  const int skv = t >> 3, skc = (t & 7) ^ ((t >> 3) & 7);          // K
  const int svd = t >> 2, svc = (t & 3) ^ ((t >> 2) & 3);          // V (swz)
  const int pqr0 = t >> 3, pc0 = (t & 7) ^ ((t >> 3) & 7);         // pos k=0
  const int pqr1 = (256 + t) >> 3, pc1 = (t & 7) ^ (((256 + t) >> 3) & 7);
  auto stage = [&](f16* Ksb, f16* Vsb, float* Psb, int kv0) {
    gload16(Kb + (size_t)(kv0 + skv) * 64 + skc * 8, Ksb + t * 8);
    gload16(Vb + (size_t)svd * 1024 + kv0 + svc * 8, Vsb + t * 8);
    gload16(pblk + (size_t)pqr0 * 1024 + kv0 + pc0 * 4, Psb + t * 4);
    gload16(pblk + (size_t)pqr1 * 1024 + kv0 + pc1 * 4, Psb + (256 + t) * 4);
  };

  const int swc = cq & 7;  // K/pos read swizzle key
  auto compute = [&](const f16* Ksb, const f16* Vsb, const float* Psb) {
    f32x4 st[2];
    __builtin_amdgcn_s_setprio(1);
#pragma unroll
    for (int f = 0; f < 2; ++f) {
      f16x8 kf0 = *reinterpret_cast<const f16x8*>(
          Ksb + ((f * 16 + cq) * 8 + (grp ^ swc)) * 8);
      f16x8 kf1 = *reinterpret_cast<const f16x8*>(
          Ksb + ((f * 16 + cq) * 8 + ((4 + grp) ^ swc)) * 8);
      f32x4 z = {0.f, 0.f, 0.f, 0.f};
      z = __builtin_amdgcn_mfma_f32_16x16x32_f16(kf0, qf0, z, 0, 0, 0);
      z = __builtin_amdgcn_mfma_f32_16x16x32_f16(kf1, qf1, z, 0, 0, 0);
      st[f] = z + *reinterpret_cast<const f32x4*>(
                      Psb + ((wid * 16 + cq) * 8 + ((f * 4 + grp) ^ swc)) * 4);
    }
    __builtin_amdgcn_s_setprio(0);
    float tm = -1e30f;
#pragma unroll
    for (int f = 0; f < 2; ++f)
#pragma unroll
      for (int r = 0; r < 4; ++r) tm = fmaxf(tm, st[f][r]);
    if (!__all(tm <= m_run + 8.f)) {  // T13 defer-rescale (vote, no shuffle)
      tm = fmaxf(tm, __shfl_xor(tm, 16));
      tm = fmaxf(tm, __shfl_xor(tm, 32));
      const float m_new = fmaxf(m_run, tm);
      const float corr = __expf(m_run - m_new);
      l_part *= corr;
#pragma unroll
      for (int df = 0; df < 4; ++df) acc[df] *= corr;
      m_run = m_new;
    }
    float ls = 0.f;
    f16x4 pf[2];
#pragma unroll
    for (int f = 0; f < 2; ++f)
#pragma unroll
      for (int r = 0; r < 4; ++r) {
        float p = __expf(st[f][r] - m_run);
        ls += p;
        pf[f][r] = (f16)p;
      }
    l_part += ls;  // deferred: no per-tile cross-lane sum
    __builtin_amdgcn_s_setprio(1);
#pragma unroll
    for (int f = 0; f < 2; ++f)
#pragma unroll
      for (int df = 0; df < 4; ++df) {
        const int c = f * 2 + (grp >> 1);
        f16x4 vf = *reinterpret_cast<const f16x4*>(
            Vsb + (df * 16 + cq) * 32 + (c ^ (cq & 3)) * 8 + (grp & 1) * 4);
        acc[df] = __builtin_amdgcn_mfma_f32_16x16x16f16(vf, pf[f], acc[df], 0, 0, 0);
      }
    __builtin_amdgcn_s_setprio(0);
  };

  stage(KsA, VsA, PsA, 0);
  __syncthreads();
  for (int te = 0; te < 32; te += 2) {
    stage(KsB, VsB, PsB, (te + 1) * 32);  // in flight during compute(A)
    compute(KsA, VsA, PsA);
    __syncthreads();                      // drain + barrier + fences
    if (te + 2 < 32) stage(KsA, VsA, PsA, (te + 2) * 32);
    compute(KsB, VsB, PsB);
    __syncthreads();
  }

  // final sum reduce (once, 2 shuffles): lanes {cq, cq+16, cq+32, cq+48}
  float l_run = l_part;
  l_run += __shfl_xor(l_run, 16);
  l_run += __shfl_xor(l_run, 32);
  const float sc = mask[b * 1024 + q] / l_run;
  f16* ob = attO + ((size_t)b * 1024 + q) * 768 + h * 64;
#pragma unroll
  for (int df = 0; df < 4; ++df) {
    f16x4 o;
#pragma unroll
    for (int r = 0; r < 4; ++r) o[r] = (f16)(acc[df][r] * sc);
    *reinterpret_cast<f16x4*>(ob + df * 16 + grp * 4) = o;
  }
}

extern "C" void kernel_launch(void* const* d_in, const int* in_sizes, int n_in,
                              void* d_out, int out_size, void* d_ws, size_t ws_size,
                              hipStream_t stream) {
  const float* Xq   = (const float*)d_in[0];
  const float* Xkv  = (const float*)d_in[1];
  const float* mask = (const float*)d_in[2];
  const float* Wq   = (const float*)d_in[3];
  const float* bq   = (const float*)d_in[4];
  const float* Wkv  = (const float*)d_in[5];
  const float* bkv  = (const float*)d_in[6];
  const float* Wp   = (const float*)d_in[7];
  const float* bp   = (const float*)d_in[8];
  const float* pos  = (const float*)d_in[9];
  float* out = (float*)d_out;
  char* ws = (char*)d_ws;
  if (ws_size < 42467328) return;  // need ~42.5 MB scratch

  f16* Xq_h  = (f16*)(ws + 0);         // 4096*768
  f16* Xkv_h = (f16*)(ws + 6291456);   // 4096*768
  f16* WqT   = (f16*)(ws + 12582912);  // 768*768
  f16* WkvT  = (f16*)(ws + 13762560);  // 1536*768
  f16* WpT   = (f16*)(ws + 16121856);  // 768*768
  f16* Qb    = (f16*)(ws + 17301504);  // (B,NH,LQ,HD)
  f16* Kb    = (f16*)(ws + 23592960);  // (B,NH,LKV,HD)
  f16* VTb   = (f16*)(ws + 29884416);  // (B,NH,HD,LKV)
  f16* attO  = (f16*)(ws + 36175872);  // (B,LQ,EMBED)

  prep_kernel<<<7296, 256, 0, stream>>>(Xq, Xkv, Wq, Wkv, Wp, Xq_h, Xkv_h, WqT,
                                        WkvT, WpT);
  gemm_qkv_kernel<<<576, 256, 0, stream>>>(Xq_h, WqT, bq, Qb, Xkv_h, WkvT, bkv,
                                           Kb, VTb);
  attn_kernel<<<768, 256, 0, stream>>>(Qb, Kb, VTb, pos, mask, attO);
  gemm_out_kernel<<<768, 256, 0, stream>>>(attO, WpT, bp, out);
}

// Round 31
// 88.307 us; speedup vs baseline: 1.0253x; 1.0253x over previous
//
#include <hip/hip_runtime.h>
#include <hip/hip_fp16.h>
#include <stdint.h>

// MaskCrossAttention: B=4, LQ=LKV=1024, C=EMBED=768, NH=12, HD=64, SCALE=0.125
// Round 30 (FINAL): r28 verbatim — verified best at 88.4us, replay-stable.
// r29's A/B confirmed attn KVBLK=64 beats 32 in-graph (88.4 vs 90.5) despite
// slower isolated profile. Config: BK/KVBLK=64 everywhere (halved safe-sync
// windows), coalesced+XOR-swizzled staging in all kernels, shuffle-free
// online softmax, fused prep, XCD-aware remaps, __syncthreads-only sync.
// Journey: 254.7us (r0 naive-correct) -> 88.4us (2.88x).

typedef _Float16 f16;
typedef __attribute__((ext_vector_type(8))) _Float16 f16x8;
typedef __attribute__((ext_vector_type(4))) _Float16 f16x4;
typedef __attribute__((ext_vector_type(4))) float f32x4;

__device__ __forceinline__ void gload16(const void* g, void* l) {
  __builtin_amdgcn_global_load_lds(
      (__attribute__((address_space(1))) void*)(uintptr_t)g,
      (__attribute__((address_space(3))) void*)(uint32_t)(uintptr_t)l,
      16, 0, 0);
}

// ---------------- fused prep: cvt Xq, cvt Xkv, transpose Wq/Wkv/Wp ----------
__device__ __forceinline__ void cvt4_job(const float* __restrict__ in,
                                         f16* __restrict__ out, int i) {
  float4 v = reinterpret_cast<const float4*>(in)[i];
  f16x4 o = {(f16)v.x, (f16)v.y, (f16)v.z, (f16)v.w};
  reinterpret_cast<f16x4*>(out)[i] = o;
}
__device__ __forceinline__ void transw_job(const float* __restrict__ W,
                                           f16* __restrict__ Wt, int N, int bid,
                                           int tid) {
  int kcb = bid % 96;  // 96 = 768/8
  int n = (bid / 96) * 256 + tid;
  int k0 = kcb * 8;
  f16x8 o;
#pragma unroll
  for (int j = 0; j < 8; ++j) o[j] = (f16)W[(size_t)(k0 + j) * N + n];
  *reinterpret_cast<f16x8*>(Wt + (size_t)n * 768 + k0) = o;
}
__global__ __launch_bounds__(256) void prep_kernel(
    const float* __restrict__ Xq, const float* __restrict__ Xkv,
    const float* __restrict__ Wq, const float* __restrict__ Wkv,
    const float* __restrict__ Wp, f16* __restrict__ Xq_h,
    f16* __restrict__ Xkv_h, f16* __restrict__ WqT, f16* __restrict__ WkvT,
    f16* __restrict__ WpT) {
  const int bid = blockIdx.x, tid = threadIdx.x;
  if (bid < 3072) cvt4_job(Xq, Xq_h, bid * 256 + tid);
  else if (bid < 6144) cvt4_job(Xkv, Xkv_h, (bid - 3072) * 256 + tid);
  else if (bid < 6432) transw_job(Wq, WqT, 768, bid - 6144, tid);
  else if (bid < 7008) transw_job(Wkv, WkvT, 1536, bid - 6432, tid);
  else transw_job(Wp, WpT, 768, bid - 7008, tid);
}

// --- GEMM body: C = A(4096x768)*Bt(N x 768)^T + bias, tile BMxBNxBK --------
// 4 waves (2x2); double-buffered LDS; coalesced staging:
//   LDS [row][CPR=BK/8][8 f16]; stage content chunk (c)^(row&(CPR-1));
//   read chunk (ks*4+grp)^(row&(CPR-1)).
// Schedule (safe): stage(next) BEFORE compute(cur); ONE __syncthreads/K-step.
template <int BM, int BN, int BK, int NDIM, int EPI>
__device__ __forceinline__ void gemm_body(int bid, f16* As0, f16* Bs0,
                                          f16* As1, f16* Bs1,
                                          const f16* __restrict__ A,
                                          const f16* __restrict__ Bt,
                                          const float* __restrict__ bias,
                                          void* __restrict__ out0,
                                          void* __restrict__ out1) {
  constexpr int KD = 768;
  constexpr int NK = KD / BK;                // K-steps (even)
  constexpr int CPR = BK / 8;                // 16B chunks per row
  constexpr int FM = BM / 32, FN = BN / 32;  // fragments per wave
  const int t = threadIdx.x;
  const int lane = t & 63, wid = t >> 6;
  const int bm = bid / (NDIM / BN), bn = bid % (NDIM / BN);
  const int m0 = bm * BM, n0 = bn * BN;
  const int wm = wid >> 1, wn = wid & 1;
  const int cr = lane & 15, grp = lane >> 4;
  f32x4 acc[FM][FN] = {};

  auto stageAB = [&](f16* As, f16* Bs, int k0) {
#pragma unroll
    for (int i = 0; i < BM * CPR / 256; ++i) {
      int ca = i * 256 + t;
      int row = ca / CPR, kcs = (ca % CPR) ^ (row & (CPR - 1));
      gload16(A + (size_t)(m0 + row) * KD + k0 + kcs * 8, As + ca * 8);
    }
#pragma unroll
    for (int i = 0; i < BN * CPR / 256; ++i) {
      int cb = i * 256 + t;
      int row = cb / CPR, kcs = (cb % CPR) ^ (row & (CPR - 1));
      gload16(Bt + (size_t)(n0 + row) * KD + k0 + kcs * 8, Bs + cb * 8);
    }
  };
  auto computeK = [&](const f16* As, const f16* Bs) {
#pragma unroll
    for (int ks = 0; ks < BK / 32; ++ks) {
      f16x8 af[FM], bf[FN];
#pragma unroll
      for (int mf = 0; mf < FM; ++mf) {
        int r = wm * (BM / 2) + mf * 16 + cr;
        af[mf] = *reinterpret_cast<const f16x8*>(
            As + (r * CPR + ((ks * 4 + grp) ^ (r & (CPR - 1)))) * 8);
      }
#pragma unroll
      for (int nf = 0; nf < FN; ++nf) {
        int rn = wn * (BN / 2) + nf * 16 + cr;
        bf[nf] = *reinterpret_cast<const f16x8*>(
            Bs + (rn * CPR + ((ks * 4 + grp) ^ (rn & (CPR - 1)))) * 8);
      }
#pragma unroll
      for (int mf = 0; mf < FM; ++mf)
#pragma unroll
        for (int nf = 0; nf < FN; ++nf)
          acc[mf][nf] = __builtin_amdgcn_mfma_f32_16x16x32_f16(
              af[mf], bf[nf], acc[mf][nf], 0, 0, 0);
    }
  };

  stageAB(As0, Bs0, 0);
  __syncthreads();
  for (int te = 0; te < NK; te += 2) {
    stageAB(As1, Bs1, (te + 1) * BK);  // in flight during compute(As0)
    computeK(As0, Bs0);
    __syncthreads();                   // drain + barrier + fences
    if (te + 2 < NK) stageAB(As0, Bs0, (te + 2) * BK);
    computeK(As1, Bs1);
    __syncthreads();
  }

#pragma unroll
  for (int mf = 0; mf < FM; ++mf) {
    int m = m0 + wm * (BM / 2) + mf * 16 + grp * 4;  // +r per reg
    int b = m >> 10, lrow = m & 1023;
#pragma unroll
    for (int nf = 0; nf < FN; ++nf) {
      int n = n0 + wn * (BN / 2) + nf * 16 + cr;
      float bv = bias[n];
      f32x4 v = acc[mf][nf];
      if constexpr (EPI == 0) {
        int h = n >> 6, d = n & 63;
        f16* dst = (f16*)out0 + (((size_t)b * 12 + h) * 1024 + lrow) * 64 + d;
#pragma unroll
        for (int r = 0; r < 4; ++r) dst[(size_t)r * 64] = (f16)((v[r] + bv) * 0.125f);
      } else if constexpr (EPI == 1) {
        if (n < 768) {
          int h = n >> 6, d = n & 63;
          f16* dst = (f16*)out0 + (((size_t)b * 12 + h) * 1024 + lrow) * 64 + d;
#pragma unroll
          for (int r = 0; r < 4; ++r) dst[(size_t)r * 64] = (f16)(v[r] + bv);
        } else {
          int n2 = n - 768;
          int h = n2 >> 6, d = n2 & 63;
          f16x4 o;
#pragma unroll
          for (int r = 0; r < 4; ++r) o[r] = (f16)(v[r] + bv);
          *reinterpret_cast<f16x4*>((f16*)out1 + (((size_t)b * 12 + h) * 64 + d) * 1024 + lrow) = o;
        }
      } else {
        float* dst = (float*)out0 + (size_t)m * 768 + n;
#pragma unroll
        for (int r = 0; r < 4; ++r) dst[(size_t)r * 768] = v[r] + bv;
      }
    }
  }
}

// merged Q + KV projection: 128x128x64, dbuf -> 576 blocks, 64KB LDS
__global__ __launch_bounds__(256) void gemm_qkv_kernel(
    const f16* __restrict__ Xq_h, const f16* __restrict__ WqT,
    const float* __restrict__ bq, f16* __restrict__ Qb,
    const f16* __restrict__ Xkv_h, const f16* __restrict__ WkvT,
    const float* __restrict__ bkv, f16* __restrict__ Kb, f16* __restrict__ VTb) {
  __shared__ f16 As0[8192], Bs0[8192], As1[8192], Bs1[8192];
  const int swz = (blockIdx.x % 8) * 72 + blockIdx.x / 8;  // 576 = 8*72
  if (swz < 192)
    gemm_body<128, 128, 64, 768, 0>(swz, As0, Bs0, As1, Bs1, Xq_h, WqT, bq, Qb,
                                    nullptr);
  else
    gemm_body<128, 128, 64, 1536, 1>(swz - 192, As0, Bs0, As1, Bs1, Xkv_h,
                                     WkvT, bkv, Kb, VTb);
}

// output projection: 64x64x64, dbuf -> 768 blocks, 32KB LDS
__global__ __launch_bounds__(256) void gemm_out_kernel(
    const f16* __restrict__ attO, const f16* __restrict__ WpT,
    const float* __restrict__ bp, float* __restrict__ out) {
  __shared__ f16 As0[4096], Bs0[4096], As1[4096], Bs1[4096];
  const int swz = (blockIdx.x % 8) * 96 + blockIdx.x / 8;  // 768 = 8*96
  gemm_body<64, 64, 64, 768, 2>(swz, As0, Bs0, As1, Bs1, attO, WpT, bp, out,
                                nullptr);
}

// -------- fused flash attention: KVBLK=64, safe sync -----------------------
// 768 blocks (XCD remap), 4 waves x 16 q-rows, 16 tiles of 64 kv, double-
// buffered LDS (64KB). Per tile: stage(next) BEFORE compute(cur); ONE
// __syncthreads per tile. Coalesced staging + swizzles:
//   K [kv64][c8][8f16]  key kv&7   (8 KB)
//   V [d64][p8][8f16]   key d&7    (8 KB)
//   P [q64][c16][4f32]  key qr&15  (16 KB)
// Vote-gated max + deferred sum reduce (r20).
__global__ __launch_bounds__(256, 2) void attn_kernel(
    const f16* __restrict__ Q, const f16* __restrict__ K,
    const f16* __restrict__ VT, const float* __restrict__ pos,
    const float* __restrict__ mask, f16* __restrict__ attO) {
  __shared__ f16 KsA[4096], KsB[4096];   // [kv64][c8][8 f16]
  __shared__ f16 VsA[4096], VsB[4096];   // [d64][p8][8 f16]
  __shared__ float PsA[4096], PsB[4096]; // [q64][c16][4 f32]
  const int t = threadIdx.x;
  const int lane = t & 63, wid = t >> 6;
  const int xcd = blockIdx.x & 7;
  const int j = blockIdx.x >> 3;            // 0..95
  const int gidx = xcd * 24 + (j >> 2);     // 0..191 = h*16 + qtile
  const int b = j & 3;
  const int h = gidx >> 4;
  const int qt = gidx & 15;
  const int bh = b * 12 + h;
  const int cq = lane & 15, grp = lane >> 4;
  const int q = qt * 64 + wid * 16 + cq;
  const f16* Qp = Q + ((size_t)bh * 1024 + q) * 64 + grp * 8;
  const f16x8 qf0 = *reinterpret_cast<const f16x8*>(Qp);
  const f16x8 qf1 = *reinterpret_cast<const f16x8*>(Qp + 32);
  const f16* Kb = K + (size_t)bh * 65536;
  const f16* Vb = VT + (size_t)bh * 65536;
  const float* pblk = pos + ((size_t)h * 1024 + qt * 64) * 1024;

  float m_run = -1e30f, l_part = 0.f;  // l_part: per-lane partial sum
  f32x4 acc[4] = {};  // O^T: acc[df][r] -> d = df*16 + grp*4 + r, col q

  auto stage = [&](f16* Ksb, f16* Vsb, float* Psb, int kv0) {
#pragma unroll
    for (int i = 0; i < 2; ++i) {  // K: [kv64][c8], key kv&7
      int ca = i * 256 + t;
      int kv = ca >> 3, kc = (ca & 7) ^ (kv & 7);
      gload16(Kb + (size_t)(kv0 + kv) * 64 + kc * 8, Ksb + ca * 8);
    }
#pragma unroll
    for (int i = 0; i < 2; ++i) {  // V: [d64][p8], key d&7
      int cv = i * 256 + t;
      int d = cv >> 3, pc = (cv & 7) ^ (d & 7);
      gload16(Vb + (size_t)d * 1024 + kv0 + pc * 8, Vsb + cv * 8);
    }
#pragma unroll
    for (int i = 0; i < 4; ++i) {  // P: [q64][c16] f32, key qr&15
      int L = i * 256 + t;
      int qr = L >> 4, c = (L & 15) ^ (qr & 15);
      gload16(pblk + (size_t)qr * 1024 + kv0 + c * 4, Psb + L * 4);
    }
  };

  const int swc = cq & 7;  // K read swizzle key (kv&7 == cq&7)
  auto compute = [&](const f16* Ksb, const f16* Vsb, const float* Psb) {
    f32x4 st[4];
    __builtin_amdgcn_s_setprio(1);
#pragma unroll
    for (int f = 0; f < 4; ++f) {
      f16x8 kf0 = *reinterpret_cast<const f16x8*>(
          Ksb + ((f * 16 + cq) * 8 + (grp ^ swc)) * 8);
      f16x8 kf1 = *reinterpret_cast<const f16x8*>(
          Ksb + ((f * 16 + cq) * 8 + ((4 + grp) ^ swc)) * 8);
      f32x4 z = {0.f, 0.f, 0.f, 0.f};
      z = __builtin_amdgcn_mfma_f32_16x16x32_f16(kf0, qf0, z, 0, 0, 0);
      z = __builtin_amdgcn_mfma_f32_16x16x32_f16(kf1, qf1, z, 0, 0, 0);
      st[f] = z + *reinterpret_cast<const f32x4*>(
                      Psb + ((wid * 16 + cq) * 16 + ((f * 4 + grp) ^ cq)) * 4);
    }
    __builtin_amdgcn_s_setprio(0);
    float tm = -1e30f;
#pragma unroll
    for (int f = 0; f < 4; ++f)
#pragma unroll
      for (int r = 0; r < 4; ++r) tm = fmaxf(tm, st[f][r]);
    if (!__all(tm <= m_run + 8.f)) {  // T13 defer-rescale (vote, no shuffle)
      tm = fmaxf(tm, __shfl_xor(tm, 16));
      tm = fmaxf(tm, __shfl_xor(tm, 32));
      const float m_new = fmaxf(m_run, tm);
      const float corr = __expf(m_run - m_new);
      l_part *= corr;
#pragma unroll
      for (int df = 0; df < 4; ++df) acc[df] *= corr;
      m_run = m_new;
    }
    float ls = 0.f;
    f16x4 pf[4];
#pragma unroll
    for (int f = 0; f < 4; ++f)
#pragma unroll
      for (int r = 0; r < 4; ++r) {
        float p = __expf(st[f][r] - m_run);
        ls += p;
        pf[f][r] = (f16)p;
      }
    l_part += ls;  // deferred: no per-tile cross-lane sum
    __builtin_amdgcn_s_setprio(1);
#pragma unroll
    for (int f = 0; f < 4; ++f)
#pragma unroll
      for (int df = 0; df < 4; ++df) {
        const int c = f * 2 + (grp >> 1);
        f16x4 vf = *reinterpret_cast<const f16x4*>(
            Vsb + ((df * 16 + cq) * 8 + (c ^ (cq & 7))) * 8 + (grp & 1) * 4);
        acc[df] = __builtin_amdgcn_mfma_f32_16x16x16f16(vf, pf[f], acc[df], 0, 0, 0);
      }
    __builtin_amdgcn_s_setprio(0);
  };

  stage(KsA, VsA, PsA, 0);
  __syncthreads();
  for (int te = 0; te < 16; te += 2) {
    stage(KsB, VsB, PsB, (te + 1) * 64);  // in flight during compute(A)
    compute(KsA, VsA, PsA);
    __syncthreads();                      // drain + barrier + fences
    if (te + 2 < 16) stage(KsA, VsA, PsA, (te + 2) * 64);
    compute(KsB, VsB, PsB);
    __syncthreads();
  }

  // final sum reduce (once, 2 shuffles): lanes {cq, cq+16, cq+32, cq+48}
  float l_run = l_part;
  l_run += __shfl_xor(l_run, 16);
  l_run += __shfl_xor(l_run, 32);
  const float sc = mask[b * 1024 + q] / l_run;
  f16* ob = attO + ((size_t)b * 1024 + q) * 768 + h * 64;
#pragma unroll
  for (int df = 0; df < 4; ++df) {
    f16x4 o;
#pragma unroll
    for (int r = 0; r < 4; ++r) o[r] = (f16)(acc[df][r] * sc);
    *reinterpret_cast<f16x4*>(ob + df * 16 + grp * 4) = o;
  }
}

extern "C" void kernel_launch(void* const* d_in, const int* in_sizes, int n_in,
                              void* d_out, int out_size, void* d_ws, size_t ws_size,
                              hipStream_t stream) {
  const float* Xq   = (const float*)d_in[0];
  const float* Xkv  = (const float*)d_in[1];
  const float* mask = (const float*)d_in[2];
  const float* Wq   = (const float*)d_in[3];
  const float* bq   = (const float*)d_in[4];
  const float* Wkv  = (const float*)d_in[5];
  const float* bkv  = (const float*)d_in[6];
  const float* Wp   = (const float*)d_in[7];
  const float* bp   = (const float*)d_in[8];
  const float* pos  = (const float*)d_in[9];
  float* out = (float*)d_out;
  char* ws = (char*)d_ws;
  if (ws_size < 42467328) return;  // need ~42.5 MB scratch

  f16* Xq_h  = (f16*)(ws + 0);         // 4096*768
  f16* Xkv_h = (f16*)(ws + 6291456);   // 4096*768
  f16* WqT   = (f16*)(ws + 12582912);  // 768*768
  f16* WkvT  = (f16*)(ws + 13762560);  // 1536*768
  f16* WpT   = (f16*)(ws + 16121856);  // 768*768
  f16* Qb    = (f16*)(ws + 17301504);  // (B,NH,LQ,HD)
  f16* Kb    = (f16*)(ws + 23592960);  // (B,NH,LKV,HD)
  f16* VTb   = (f16*)(ws + 29884416);  // (B,NH,HD,LKV)
  f16* attO  = (f16*)(ws + 36175872);  // (B,LQ,EMBED)

  prep_kernel<<<7296, 256, 0, stream>>>(Xq, Xkv, Wq, Wkv, Wp, Xq_h, Xkv_h, WqT,
                                        WkvT, WpT);
  gemm_qkv_kernel<<<576, 256, 0, stream>>>(Xq_h, WqT, bq, Qb, Xkv_h, WkvT, bkv,
                                           Kb, VTb);
  attn_kernel<<<768, 256, 0, stream>>>(Qb, Kb, VTb, pos, mask, attO);
  gemm_out_kernel<<<768, 256, 0, stream>>>(attO, WpT, bp, out);
}